// Round 4
// baseline (105.655 us; speedup 1.0000x reference)
//
#include <hip/hip_runtime.h>
#include <math.h>

#define NB 8
#define NC 16
#define SIDE 64
#define CELLS 512            // 8^3
#define HALF 4096            // NB*CELLS
#define NROWS 8192           // 2*HALF
#define NCHUNK 64
#define CHUNKJ 128           // NROWS / NCHUNK
#define INV_TEMP 10.0f

#define T4 524288            // total threads in pool_stride (2048 blocks x 256)
#define PER_TENSOR4 8388608  // float4s per input tensor

// ---------------------------------------------------------------- pooling stage 1
// Copy-ubench shape: persistent grid (8 blocks/CU, 100% occupancy), 32-iteration
// grid-stride loop of single coalesced float4 loads. Each lane's float4 lies in
// one xb block (xb = (lane&15)>>1); shfl_xor{1,16,32} sums the 8 lanes sharing
// xb; even lanes <16 store 8 consecutive dwords (one 32B run) of half-cell
// partials. partial2[chunk*8+xb], chunk = global float4 index >> 6 (a 4-y-row
// quad of one plane). 2M floats = 8 MB, L2-resident.
__global__ __launch_bounds__(256) void pool_stride(const float* __restrict__ p1,
                                                   const float* __restrict__ p2,
                                                   float* __restrict__ partial2) {
    int g    = blockIdx.x * 256 + threadIdx.x;    // 0..524287
    int lane = threadIdx.x & 63;
    bool writer = (lane < 16) && ((lane & 1) == 0);
    int xb = (lane & 15) >> 1;
    #pragma unroll 1
    for (int half = 0; half < 2; ++half) {
        const float4* src4 = (const float4*)(half ? p2 : p1);
        size_t cbase = (size_t)half * (PER_TENSOR4 / 64) * 8;   // float offset into partial2
        #pragma unroll 4
        for (int it = 0; it < 16; ++it) {
            int flat = it * T4 + g;               // consecutive lanes -> consecutive float4s
            float4 v = src4[flat];
            float s = (v.x + v.y) + (v.z + v.w);
            s += __shfl_xor(s, 1);
            s += __shfl_xor(s, 16);
            s += __shfl_xor(s, 32);
            if (writer) {
                int chunk = flat >> 6;            // wave-uniform (wavebase 64-aligned)
                partial2[cbase + (size_t)chunk * 8 + xb] = s;
            }
        }
    }
}

// ---------------------------------------------------------------- pooling stage 2
// One thread per cell (p,b,c,zb,yb,xb): sum 16 half-cell partials (8 dz x 2 h)
// from the 8MB L2-resident buffer, write mm in reshape->transpose order.
__global__ __launch_bounds__(256) void pool_reduce2b(const float* __restrict__ partial2,
                                                     float* __restrict__ mm) {
    int r  = blockIdx.x * 256 + threadIdx.x;      // 0..131071
    int xb = r & 7;
    int yb = (r >> 3) & 7;
    int zb = (r >> 6) & 7;
    int c  = (r >> 9) & 15;
    int b  = (r >> 13) & 7;
    int p  = r >> 16;
    // chunk = (p*8192 + plane)*16 + qd ; plane = (b*16+c)*64 + zb*8 + dz ; qd = yb*2 + h
    size_t base = ((((size_t)p * 8192) + (size_t)(b * 16 + c) * 64 + zb * 8) * 16 + yb * 2) * 8 + xb;
    float s = 0.f;
    #pragma unroll
    for (int dz = 0; dz < 8; ++dz) {
        s += partial2[base + dz * 128];           // h = 0  (dz stride = 16 chunks = 128 floats)
        s += partial2[base + dz * 128 + 8];       // h = 1
    }
    int row = p * HALF + b * CELLS + (zb * 64 + yb * 8 + xb);
    mm[row * NC + c] = s * (1.0f / 512.0f);
}

// ---------------------------------------------------------------- MLP + normalize
__global__ __launch_bounds__(256) void mlp_kernel(const float* __restrict__ mm,
                                                  const float* __restrict__ w1,
                                                  const float* __restrict__ b1,
                                                  const float* __restrict__ w2,
                                                  const float* __restrict__ b2,
                                                  float* __restrict__ f) {
    __shared__ float sw1[256], sw2[256], sb1[16], sb2[16];
    int t = threadIdx.x;
    sw1[t] = w1[t];
    sw2[t] = w2[t];
    if (t < 16) { sb1[t] = b1[t]; sb2[t] = b2[t]; }
    __syncthreads();
    int row = blockIdx.x * 256 + t;
    float x[16];
    const float4* src = (const float4*)(mm + row * NC);
    #pragma unroll
    for (int i = 0; i < 4; ++i) {
        float4 v = src[i];
        x[i*4+0]=v.x; x[i*4+1]=v.y; x[i*4+2]=v.z; x[i*4+3]=v.w;
    }
    float h[16];
    #pragma unroll
    for (int i = 0; i < 16; ++i) {
        float a = sb1[i];
        #pragma unroll
        for (int k = 0; k < 16; ++k) a = fmaf(x[k], sw1[i*16+k], a);
        h[i] = a > 0.f ? a : 0.f;
    }
    float ff[16];
    float nrm = 0.f;
    #pragma unroll
    for (int i = 0; i < 16; ++i) {
        float a = sb2[i];
        #pragma unroll
        for (int k = 0; k < 16; ++k) a = fmaf(h[k], sw2[i*16+k], a);
        ff[i] = a;
        nrm = fmaf(a, a, nrm);
    }
    float inv = 1.0f / fmaxf(sqrtf(nrm), 1e-12f);
    float4* dst = (float4*)(f + row * NC);
    #pragma unroll
    for (int i = 0; i < 4; ++i) {
        float4 v;
        v.x = ff[i*4+0]*inv; v.y = ff[i*4+1]*inv; v.z = ff[i*4+2]*inv; v.w = ff[i*4+3]*inv;
        dst[i] = v;
    }
}

// ---------------------------------------------------------------- logits + partial expsum
__global__ __launch_bounds__(256) void lse_partial(const float* __restrict__ f,
                                                   float* __restrict__ partial,
                                                   float* __restrict__ pos) {
    __shared__ float tile[CHUNKJ * NC];             // 8 KB
    int rb = blockIdx.x >> 6;
    int ck = blockIdx.x & 63;
    int t  = threadIdx.x;
    int jbase = ck * CHUNKJ;
    {
        const float4* fsrc = (const float4*)(f + (size_t)jbase * NC);
        float4* tdst = (float4*)tile;
        tdst[t]       = fsrc[t];
        tdst[t + 256] = fsrc[t + 256];
    }
    __syncthreads();
    int r0 = rb * 1024 + t * 4;
    float fi[4][16];
    #pragma unroll
    for (int rr = 0; rr < 4; ++rr) {
        const float4* q = (const float4*)(f + (size_t)(r0 + rr) * NC);
        #pragma unroll
        for (int i = 0; i < 4; ++i) {
            float4 v = q[i];
            fi[rr][i*4+0]=v.x; fi[rr][i*4+1]=v.y; fi[rr][i*4+2]=v.z; fi[rr][i*4+3]=v.w;
        }
    }
    float s[4]  = {0.f, 0.f, 0.f, 0.f};
    float pv[4] = {0.f, 0.f, 0.f, 0.f};
    int pr[4];
    #pragma unroll
    for (int rr = 0; rr < 4; ++rr) pr[rr] = (r0 + rr + HALF) & (NROWS - 1);

    for (int jj = 0; jj < CHUNKJ; ++jj) {
        float fj[16];
        const float4* tj = (const float4*)(tile + jj * NC);
        #pragma unroll
        for (int i = 0; i < 4; ++i) {
            float4 v = tj[i];
            fj[i*4+0]=v.x; fj[i*4+1]=v.y; fj[i*4+2]=v.z; fj[i*4+3]=v.w;
        }
        int j = jbase + jj;
        #pragma unroll
        for (int rr = 0; rr < 4; ++rr) {
            float d = 0.f;
            #pragma unroll
            for (int k = 0; k < 16; ++k) d = fmaf(fi[rr][k], fj[k], d);
            float l = d * INV_TEMP;
            float e = __expf(l - INV_TEMP);          // fixed shift: max logit = 10
            s[rr] += (j == r0 + rr) ? 0.f : e;       // mask diagonal
            pv[rr] = (j == pr[rr]) ? l : pv[rr];     // capture positive
        }
    }
    #pragma unroll
    for (int rr = 0; rr < 4; ++rr) {
        int r = r0 + rr;
        partial[(size_t)r * NCHUNK + ck] = s[rr];
        if (pr[rr] >= jbase && pr[rr] < jbase + CHUNKJ) pos[r] = pv[rr];
    }
}

// ---------------------------------------------------------------- per-row lse + block sums
__global__ __launch_bounds__(256) void lse_finish(const float* __restrict__ partial,
                                                  const float* __restrict__ pos,
                                                  float* __restrict__ bsum) {
    int r = blockIdx.x * 256 + threadIdx.x;
    const float4* q = (const float4*)(partial + (size_t)r * NCHUNK);
    float s = 0.f;
    #pragma unroll
    for (int i = 0; i < 16; ++i) {
        float4 v = q[i];
        s += (v.x + v.y) + (v.z + v.w);
    }
    float val = (logf(s) + INV_TEMP) - pos[r];
    __shared__ float red[256];
    red[threadIdx.x] = val;
    __syncthreads();
    for (int off = 128; off > 0; off >>= 1) {
        if (threadIdx.x < off) red[threadIdx.x] += red[threadIdx.x + off];
        __syncthreads();
    }
    if (threadIdx.x == 0) bsum[blockIdx.x] = red[0];
}

__global__ void final_mean(const float* __restrict__ bsum, float* __restrict__ out) {
    if (threadIdx.x == 0) {
        float s = 0.f;
        for (int i = 0; i < 32; ++i) s += bsum[i];
        out[0] = s * (1.0f / (float)NROWS);
    }
}

// ---------------------------------------------------------------- launch
extern "C" void kernel_launch(void* const* d_in, const int* in_sizes, int n_in,
                              void* d_out, int out_size, void* d_ws, size_t ws_size,
                              hipStream_t stream) {
    const float* p1 = (const float*)d_in[0];
    const float* p2 = (const float*)d_in[1];
    const float* w1 = (const float*)d_in[2];
    const float* b1 = (const float*)d_in[3];
    const float* w2 = (const float*)d_in[4];
    const float* b2 = (const float*)d_in[5];
    float* out = (float*)d_out;

    char* ws = (char*)d_ws;
    // partial2 (8 MB, pool stage-1 output) is dead after pool_reduce2b; the
    // lse buffers reuse its space (stream-ordered, no overlap in lifetime).
    float* partial2 = (float*)(ws);                               // 8 MB
    float* lsepart  = (float*)(ws);                               // 2 MB (reuses partial2)
    float* pos      = (float*)(ws + 2 * 1024 * 1024);             // 32 KB
    float* bsum     = (float*)(ws + 2 * 1024 * 1024 + 64 * 1024); // 128 B
    float* mm       = (float*)(ws + 8 * 1024 * 1024);             // 512 KB
    float* f        = (float*)(ws + 8 * 1024 * 1024 + 512 * 1024);// 512 KB

    hipLaunchKernelGGL(pool_stride,   dim3(2048), dim3(256), 0, stream, p1, p2, partial2);
    hipLaunchKernelGGL(pool_reduce2b, dim3(512),  dim3(256), 0, stream, partial2, mm);
    hipLaunchKernelGGL(mlp_kernel,    dim3(32),   dim3(256), 0, stream, mm, w1, b1, w2, b2, f);
    hipLaunchKernelGGL(lse_partial,   dim3(512),  dim3(256), 0, stream, f, lsepart, pos);
    hipLaunchKernelGGL(lse_finish,    dim3(32),   dim3(256), 0, stream, lsepart, pos, bsum);
    hipLaunchKernelGGL(final_mean,    dim3(1),    dim3(64),  0, stream, bsum, out);
}